// Round 11
// baseline (527.214 us; speedup 1.0000x reference)
//
#include <hip/hip_runtime.h>
#include <hip/hip_bf16.h>
#include <cstdint>
#include <cstddef>

// Problem constants (B=16, S=1024, D=1024); inputs f32, output f32 (verified r4)
#define S_LEN   1024
#define D_DIM   1024
#define QK_DIM  128
#define EXP_DIM 2048
#define H_HEADS 8
#define DH_Q    16
#define DH_V    128
#define M_ROWS  16384         // B*S

typedef __bf16 bf16;
typedef __bf16 b16x4 __attribute__((ext_vector_type(4)));
typedef __bf16 b16x8 __attribute__((ext_vector_type(8)));
typedef float  fx4   __attribute__((ext_vector_type(4)));
typedef float  f32x16 __attribute__((ext_vector_type(16)));

// ---------- async global->LDS (16B per lane) ----------
__device__ __forceinline__ void load_lds16(const bf16* g, bf16* l) {
    __builtin_amdgcn_global_load_lds(
        (const __attribute__((address_space(1))) void*)g,
        (__attribute__((address_space(3))) void*)l, 16, 0, 0);
}

// ---------- convert f32 -> bf16, 4 elements/thread ----------
__global__ __launch_bounds__(256) void convert_kernel(const float* __restrict__ src,
                                                      bf16* __restrict__ dst, int n4) {
    const int i = blockIdx.x * 256 + threadIdx.x;
    if (i >= n4) return;
    const fx4 v = ((const fx4*)src)[i];
    b16x4 o;
#pragma unroll
    for (int k = 0; k < 4; ++k) o[k] = (bf16)v[k];
    ((b16x4*)dst)[i] = o;
}

// ---------- convert expand_w f32 -> bf16 with lin/pre row interleave ----------
// rows 0..255 unchanged (q,k). Rows 256..: chunk c: out[256+32c+j] =
// lin[256+16c+j] (j<16) else pre[2304+16c+j-16]. Pairs lin/pre cols into the
// same thread of the fused GEMM (acc[mi][2p] vs acc[mi][2p+1]).
__global__ __launch_bounds__(256) void convert_expand_kernel(const float* __restrict__ src,
                                                             bf16* __restrict__ dst) {
    const int i = blockIdx.x * 256 + threadIdx.x;   // fx4 index; grid covers 4352*256 exactly
    const int orow = i >> 8, col = i & 255;
    int irow;
    if (orow < 256) {
        irow = orow;
    } else {
        const int t = orow - 256;
        const int c = t >> 5, j = t & 31;
        irow = (j < 16) ? (256 + c * 16 + j) : (2304 + c * 16 + (j - 16));
    }
    const fx4 v = ((const fx4*)src)[irow * 256 + col];
    b16x4 o;
#pragma unroll
    for (int k = 0; k < 4; ++k) o[k] = (bf16)v[k];
    ((b16x4*)dst)[i] = o;
}

// ---------- LayerNorm: x (f32) -> xn (bf16) ----------
__global__ __launch_bounds__(256) void ln_kernel(const float* __restrict__ x,
                                                 const float* __restrict__ w,
                                                 bf16* __restrict__ xn) {
    const int row = blockIdx.x;
    const int tid = threadIdx.x;
    const fx4 t = ((const fx4*)x)[(size_t)row * 256 + tid];
    float v[4];
    float s = 0.f, ss = 0.f;
#pragma unroll
    for (int i = 0; i < 4; ++i) { v[i] = t[i]; s += v[i]; ss += v[i] * v[i]; }
#pragma unroll
    for (int off = 32; off >= 1; off >>= 1) {
        s  += __shfl_xor(s,  off);
        ss += __shfl_xor(ss, off);
    }
    __shared__ float ls[4], lss[4];
    const int wave = tid >> 6;
    if ((tid & 63) == 0) { ls[wave] = s; lss[wave] = ss; }
    __syncthreads();
    s  = ls[0]  + ls[1]  + ls[2]  + ls[3];
    ss = lss[0] + lss[1] + lss[2] + lss[3];
    const float mu  = s * (1.f / D_DIM);
    const float var = ss * (1.f / D_DIM) - mu * mu;
    const float r   = rsqrtf(var + 1e-5f);
    const fx4 w4 = ((const fx4*)w)[tid];
    b16x4 o4;
#pragma unroll
    for (int i = 0; i < 4; ++i) o4[i] = (bf16)((v[i] - mu) * r * w4[i]);
    ((b16x4*)(xn + (size_t)row * D_DIM))[tid] = o4;
}

__device__ __forceinline__ float gelu_exact(float x) {
    return 0.5f * x * (1.f + erff(x * 0.70710678118654752f));
}

// ---------- clustered XCD tile map (works for MT%32==0, NT%4==0) ----------
__device__ __forceinline__ void tile_map(int& tm, int& tn) {
    const int NT = gridDim.x, MT = gridDim.y;
    const int lin = blockIdx.y * NT + blockIdx.x;
    if ((MT & 31) == 0 && (NT & 3) == 0) {
        const int xcd = lin & 7, slot = lin >> 3;
        const int MB  = MT >> 3;
        const int cnc = NT >> 2;                 // clusters per row
        const int c = slot >> 4, w = slot & 15;  // 16 blocks per 4x4 cluster
        const int cm = c / cnc, cn = c - cm * cnc;
        tm = xcd * MB + cm * 4 + (w >> 2);
        tn = cn * 4 + (w & 3);
    } else { tm = blockIdx.y; tn = blockIdx.x; }
}

// tile_map for 256-tiles: MT=64 (MT&31==0 holds), NT in {16,4} -> same code.
__device__ __forceinline__ void tile_map256(int& tm, int& tn) {
    const int NT = gridDim.x, MT = gridDim.y;
    const int lin = blockIdx.y * NT + blockIdx.x;
    if ((MT & 31) == 0 && (NT & 3) == 0) {
        const int xcd = lin & 7, slot = lin >> 3;
        const int MB  = MT >> 3;
        const int cnc = NT >> 2;
        const int c = slot >> 4, w = slot & 15;
        const int cm = c / cnc, cn = c - cm * cnc;
        tm = xcd * MB + cm * 4 + (w >> 2);
        tn = cn * 4 + (w & 3);
    } else { tm = blockIdx.y; tn = blockIdx.x; }
}

// ---------- legacy GEMM (m97-style, 128x128, BK=32) -- used for q/k (N=256) ----------
template <int EPI>
__global__ __launch_bounds__(256) void gemm_bt(const bf16* __restrict__ A,
                                               const bf16* __restrict__ W,
                                               const float* __restrict__ R,
                                               bf16* __restrict__ C,
                                               bf16* __restrict__ VH,
                                               float* __restrict__ OutF,
                                               int M, int N, int K) {
    __shared__ bf16 As[128 * 32];
    __shared__ bf16 Ws[128 * 32];
    const int tid  = threadIdx.x;
    const int wave = tid >> 6, lane = tid & 63;
    int tmi, tni;
    tile_map(tmi, tni);
    const int tile_n = tni * 128;
    const int tile_m = tmi * 128;
    const int m_off = (wave >> 1) * 64, n_off = (wave & 1) * 64;

    fx4 acc[4][4] = {};

    const int c0 = wave * 128 + lane;
    const int c1 = c0 + 64;
    const int r0 = c0 >> 2, cc0 = (c0 & 3) * 8;
    const int r1 = c1 >> 2, cc1 = (c1 & 3) * 8;

    const int mrow = lane & 15, quad = lane >> 4;

    for (int k0 = 0; k0 < K; k0 += 32) {
        load_lds16(A + (size_t)(tile_m + r0) * K + k0 + cc0, &As[c0 * 8]);
        load_lds16(A + (size_t)(tile_m + r1) * K + k0 + cc1, &As[c1 * 8]);
        load_lds16(W + (size_t)(tile_n + r0) * K + k0 + cc0, &Ws[c0 * 8]);
        load_lds16(W + (size_t)(tile_n + r1) * K + k0 + cc1, &Ws[c1 * 8]);
        __syncthreads();

        b16x8 af[4], bfr[4];
#pragma unroll
        for (int i = 0; i < 4; ++i) {
            af[i]  = *(const b16x8*)&As[(m_off + i * 16 + mrow) * 32 + quad * 8];
            bfr[i] = *(const b16x8*)&Ws[(n_off + i * 16 + mrow) * 32 + quad * 8];
        }
#pragma unroll
        for (int mi = 0; mi < 4; ++mi)
#pragma unroll
            for (int ni = 0; ni < 4; ++ni)
                acc[mi][ni] = __builtin_amdgcn_mfma_f32_16x16x32_bf16(
                    af[mi], bfr[ni], acc[mi][ni], 0, 0, 0);
        __syncthreads();
    }

    const int lcol = lane & 15, lrow4 = (lane >> 4) * 4;
#pragma unroll
    for (int mi = 0; mi < 4; ++mi)
#pragma unroll
        for (int ni = 0; ni < 4; ++ni)
#pragma unroll
            for (int r = 0; r < 4; ++r) {
                const int gr = tile_m + m_off + mi * 16 + lrow4 + r;
                const int gc = tile_n + n_off + ni * 16 + lcol;
                const float a = acc[mi][ni][r];
                if (EPI == 0) {
                    C[(size_t)gr * N + gc] = (bf16)a;
                } else if (EPI == 1) {
                    const size_t idx = (size_t)gr * N + gc;
                    OutF[idx] = a + R[idx];
                }
            }
}

// ---------- 8-phase 256x256 GEMM, BK=64, 8 waves, counted vmcnt (T3+T4) ----------
// Verified r10: 159 us, MfmaUtil 38%, SQ_LDS_BANK_CONFLICT=0. Frozen.
__device__ __forceinline__ b16x8 lds_frag_swz(const bf16* buf, int r, int colb) {
    const int p = (r << 7) + ((((colb >> 4) ^ r) & 7) << 4) + (colb & 15);
    return *(const b16x8*)((const char*)buf + p);
}

template <int EPI>
__global__ __launch_bounds__(512, 2) void gemm256(const bf16* __restrict__ A,
                                                  const bf16* __restrict__ W,
                                                  const float* __restrict__ R,
                                                  bf16* __restrict__ C,
                                                  bf16* __restrict__ VH,
                                                  float* __restrict__ OutF,
                                                  int M, int N, int K) {
    __shared__ bf16 Abuf[2][16384];   // 2 x 32KB (256 rows x 64 cols)
    __shared__ bf16 Bbuf[2][16384];
    const int tid  = threadIdx.x;
    const int wave = tid >> 6, lane = tid & 63;
    const int wm = wave >> 2, wn = wave & 3;     // 2x4 wave grid
    const int l15 = lane & 15, quad = lane >> 4;

    int tmi, tni;
    tile_map256(tmi, tni);
    const int tile_m = tmi * 256, tile_n = tni * 256;

    const int srow = tid >> 3;                                  // 0..63
    const int scol = (((tid & 7) ^ ((tid >> 3) & 7))) * 8;      // 0..56
    size_t offA[4], offB[4];
#pragma unroll
    for (int s = 0; s < 4; ++s) {
        offA[s] = (size_t)(tile_m + s * 64 + srow) * K + scol;
        offB[s] = (size_t)(tile_n + s * 64 + srow) * K + scol;
    }
    const int ldst = tid * 16;   // linear dest byte offset within each 8KB slot

    fx4 acc[8][4] = {};

    const int ntk = K >> 6;
    // prologue: stage tile 0 into buffer 0, issue order = consumption order:
    // A0, A2 (ph0 A-reads) | B0..B3 (ph0/1/3 B-reads) | A1, A3 (ph2 A-reads)
    {
        char* a0 = (char*)&Abuf[0][0] + ldst;
        char* b0 = (char*)&Bbuf[0][0] + ldst;
        load_lds16(A + offA[0], (bf16*)(a0));
        load_lds16(A + offA[2], (bf16*)(a0 + 16384));
        load_lds16(W + offB[0], (bf16*)(b0));
        load_lds16(W + offB[1], (bf16*)(b0 + 8192));
        load_lds16(W + offB[2], (bf16*)(b0 + 16384));
        load_lds16(W + offB[3], (bf16*)(b0 + 24576));
        load_lds16(A + offA[1], (bf16*)(a0 + 8192));
        load_lds16(A + offA[3], (bf16*)(a0 + 24576));
    }

    for (int t = 0; t < ntk; ++t) {
        const int nb = t & 1;
        const int kt1 = (t + 1) << 6;
        const bool pf = (t + 1 < ntk);
        const bf16* ab = &Abuf[nb][0];
        const bf16* bb = &Bbuf[nb][0];
        char* adst = (char*)&Abuf[nb ^ 1][0] + ldst;
        char* bdst = (char*)&Bbuf[nb ^ 1][0] + ldst;

        b16x8 af[4][2];    // A fragments, one mi-half at a time
        b16x8 bfv[2][2];   // B fragments, one ni-half at a time

        // ---- PH0: wait {A0,A2,B*}(t) | read A mi0-3 + B ni0-1 | stage A0,A2(t+1) | MFMA Q00
        asm volatile("s_waitcnt vmcnt(2)" ::: "memory");
        __builtin_amdgcn_s_barrier();
        __builtin_amdgcn_sched_barrier(0);
#pragma unroll
        for (int mi = 0; mi < 4; ++mi)
#pragma unroll
            for (int kk = 0; kk < 2; ++kk)
                af[mi][kk] = lds_frag_swz(ab, wm * 128 + mi * 16 + l15, kk * 64 + quad * 16);
#pragma unroll
        for (int ni = 0; ni < 2; ++ni)
#pragma unroll
            for (int kk = 0; kk < 2; ++kk)
                bfv[ni][kk] = lds_frag_swz(bb, wn * 64 + ni * 16 + l15, kk * 64 + quad * 16);
        if (pf) {
            load_lds16(A + offA[0] + kt1, (bf16*)(adst));
            load_lds16(A + offA[2] + kt1, (bf16*)(adst + 16384));
        }
        __builtin_amdgcn_s_setprio(1);
#pragma unroll
        for (int mi = 0; mi < 4; ++mi)
#pragma unroll
            for (int ni = 0; ni < 2; ++ni)
#pragma unroll
                for (int kk = 0; kk < 2; ++kk)
                    acc[mi][ni] = __builtin_amdgcn_mfma_f32_16x16x32_bf16(
                        af[mi][kk], bfv[ni][kk], acc[mi][ni], 0, 0, 0);
        __builtin_amdgcn_s_setprio(0);

        // ---- PH1: read B ni2-3 | stage B0..B3(t+1) | MFMA Q01
        __builtin_amdgcn_s_barrier();
        __builtin_amdgcn_sched_barrier(0);
#pragma unroll
        for (int ni = 0; ni < 2; ++ni)
#pragma unroll
            for (int kk = 0; kk < 2; ++kk)
                bfv[ni][kk] = lds_frag_swz(bb, wn * 64 + (ni + 2) * 16 + l15, kk * 64 + quad * 16);
        if (pf) {
            load_lds16(W + offB[0] + kt1, (bf16*)(bdst));
            load_lds16(W + offB[1] + kt1, (bf16*)(bdst + 8192));
            load_lds16(W + offB[2] + kt1, (bf16*)(bdst + 16384));
            load_lds16(W + offB[3] + kt1, (bf16*)(bdst + 24576));
        }
        __builtin_amdgcn_s_setprio(1);
#pragma unroll
        for (int mi = 0; mi < 4; ++mi)
#pragma unroll
            for (int ni = 0; ni < 2; ++ni)
#pragma unroll
                for (int kk = 0; kk < 2; ++kk)
                    acc[mi][ni + 2] = __builtin_amdgcn_mfma_f32_16x16x32_bf16(
                        af[mi][kk], bfv[ni][kk], acc[mi][ni + 2], 0, 0, 0);
        __builtin_amdgcn_s_setprio(0);

        // ---- PH2: wait {A1,A3}(t) | read A mi4-7 | stage A1,A3(t+1) | MFMA (mi4-7 x ni2-3)
        if (pf) asm volatile("s_waitcnt vmcnt(6)" ::: "memory");
        else    asm volatile("s_waitcnt vmcnt(0)" ::: "memory");
        __builtin_amdgcn_s_barrier();
        __builtin_amdgcn_sched_barrier(0);
#pragma unroll
        for (int mi = 0; mi < 4; ++mi)
#pragma unroll
            for (int kk = 0; kk < 2; ++kk)
                af[mi][kk] = lds_frag_swz(ab, wm * 128 + (mi + 4) * 16 + l15, kk * 64 + quad * 16);
        if (pf) {
            load_lds16(A + offA[1] + kt1, (bf16*)(adst + 8192));
            load_lds16(A + offA[3] + kt1, (bf16*)(adst + 24576));
        }
        __builtin_amdgcn_s_setprio(1);
#pragma unroll
        for (int mi = 0; mi < 4; ++mi)
#pragma unroll
            for (int ni = 0; ni < 2; ++ni)
#pragma unroll
                for (int kk = 0; kk < 2; ++kk)
                    acc[mi + 4][ni + 2] = __builtin_amdgcn_mfma_f32_16x16x32_bf16(
                        af[mi][kk], bfv[ni][kk], acc[mi + 4][ni + 2], 0, 0, 0);
        __builtin_amdgcn_s_setprio(0);

        // ---- PH3: read B ni0-1 | MFMA (mi4-7 x ni0-1)
        __builtin_amdgcn_s_barrier();
        __builtin_amdgcn_sched_barrier(0);
#pragma unroll
        for (int ni = 0; ni < 2; ++ni)
#pragma unroll
            for (int kk = 0; kk < 2; ++kk)
                bfv[ni][kk] = lds_frag_swz(bb, wn * 64 + ni * 16 + l15, kk * 64 + quad * 16);
        __builtin_amdgcn_s_setprio(1);
#pragma unroll
        for (int mi = 0; mi < 4; ++mi)
#pragma unroll
            for (int ni = 0; ni < 2; ++ni)
#pragma unroll
                for (int kk = 0; kk < 2; ++kk)
                    acc[mi + 4][ni] = __builtin_amdgcn_mfma_f32_16x16x32_bf16(
                        af[mi][kk], bfv[ni][kk], acc[mi + 4][ni], 0, 0, 0);
        __builtin_amdgcn_s_setprio(0);
        __builtin_amdgcn_s_barrier();
        __builtin_amdgcn_sched_barrier(0);
    }

    // ---- epilogue ----
    const int rbase = tile_m + wm * 128 + quad * 4;
    if (EPI == 2) {
        const int gb = ((tile_n + wn * 64) >> 1) + l15;
#pragma unroll
        for (int mi = 0; mi < 8; ++mi)
#pragma unroll
            for (int np = 0; np < 2; ++np) {
                const int gcol = gb + np * 16;
#pragma unroll
                for (int r = 0; r < 4; ++r) {
                    const int gr = rbase + mi * 16 + r;
                    const float l = acc[mi][2 * np][r];
                    const float p = acc[mi][2 * np + 1][r];
                    const float g = l * gelu_exact(p);
                    if (gcol < 1024) C[(size_t)gr * 2048 + gcol] = (bf16)g;
                    else             VH[(size_t)gr * 1024 + (gcol - 1024)] = (bf16)g;
                }
            }
    } else {
#pragma unroll
        for (int mi = 0; mi < 8; ++mi)
#pragma unroll
            for (int ni = 0; ni < 4; ++ni)
#pragma unroll
                for (int r = 0; r < 4; ++r) {
                    const int gr = rbase + mi * 16 + r;
                    const int gc = tile_n + wn * 64 + ni * 16 + l15;
                    const float a = acc[mi][ni][r];
                    if (EPI == 0) {
                        C[(size_t)gr * N + gc] = (bf16)a;
                    } else {
                        const size_t idx = (size_t)gr * N + gc;
                        OutF[idx] = a + R[idx];
                    }
                }
    }
}

// ---------- MFMA flash attention (QBLK=128, 8 waves, T14 cross-tile prefetch) ----------
// Loop rewritten from continue-skip to explicit next-active jump:
// active(k0) = (k0 <= qmax) || (qmax >= fi && k0+63 >= li). Band start
// hs = li & ~63 (first 64-mult >= li-63). Jump: nk=k0+64; if nk>qmax:
// nk = (qmax>=fi) ? max(nk,hs) : S. Reproduces the original active set and
// skips inactive tiles' barriers. V-regs (v8p) + K-frag (kfp) for the NEXT
// tile are loaded during the softmax phase; at tile top only the LDS writes
// remain -> HBM/L2 latency hides under softmax+PV (T14). Reg hazards: v8p/
// kfp consumed (Vt-write / QK^T) before prefetch overwrites them. Vt write
// ordering vs PV reads unchanged (write < sync2 < sync3 < read; prev read <
// sync1 < write). T5 setprio around the PV MFMA cluster.
__global__ __launch_bounds__(512) void attn_kernel(const bf16* __restrict__ qk,
                                                   const bf16* __restrict__ vh,
                                                   const float* __restrict__ pbmv,
                                                   const int* __restrict__ fip,
                                                   const int* __restrict__ lip,
                                                   bf16* __restrict__ concatb) {
    const int lin = blockIdx.y * gridDim.x + blockIdx.x;   // gridDim = (64,16)
    const int xcd = lin & 7, slot = lin >> 3;              // slot 0..127
    const int bh = xcd * 16 + (slot >> 3);
    const int qt = slot & 7;
    const int b = bh >> 3, h = bh & 7;
    const int q0 = qt * 128;
    const int tid  = threadIdx.x;
    const int wave = tid >> 6, lane = tid & 63;
    const int lm = lane & 31, lh = lane >> 5;
    const int qq = wave >> 1, sect = wave & 1;

    __shared__ float Ps[128][68];
    __shared__ bf16  Pb[128][72];
    __shared__ bf16  Vt[128][72];
    __shared__ float Mrow[128], Lrow[128], Arow[128];

    const float pm = pbmv[0];
    const float sp = (pm > 20.f) ? pm : log1pf(expf(pm));
    int fi = fip[0], li = lip[0];
    if (fi >= S_LEN) fi = 0;
    if (li >= S_LEN) li = 0;
    const int hs = li & ~63;     // first band tile (k0+63 >= li)

    const b16x8 qfrag = *(const b16x8*)(qk
        + ((size_t)(b * S_LEN + q0 + qq * 32 + lm)) * 256 + h * DH_Q + lh * 8);

    f32x16 accO[2] = {};
    if (tid < 128) { Mrow[tid] = -3e38f; Lrow[tid] = 0.f; }

    const int vkey = tid & 63;
    const int vd   = (tid >> 6) * 16;
    const int srow = wave * 16 + (lane >> 2);
    const int skq  = (lane & 3) * 16;

    const int qmax = q0 + 127;

    // prefetch tile 0 (always active: 0 <= qmax)
    const bf16* vbase = vh + ((size_t)(b * S_LEN + vkey)) * D_DIM + h * DH_V + vd;
    const bf16* kbase = qk + ((size_t)(b * S_LEN + sect * 32 + lm)) * 256 + QK_DIM + h * DH_Q + lh * 8;
    b16x8 v8p0 = *(const b16x8*)(vbase);
    b16x8 v8p1 = *(const b16x8*)(vbase + 8);
    b16x8 kfp  = *(const b16x8*)(kbase);

    for (int k0 = 0; k0 < S_LEN; ) {
        // next active tile
        int nk = k0 + 64;
        if (nk > qmax) {
            if (qmax >= fi) { if (nk < hs) nk = hs; }
            else            nk = S_LEN;
        }

        __syncthreads();   // sync1: prev PV done with Vt

        // Vt write from prefetched regs (data already in flight/landed)
#pragma unroll
        for (int j = 0; j < 8; ++j) Vt[vd + j][vkey] = v8p0[j];
#pragma unroll
        for (int j = 0; j < 8; ++j) Vt[vd + 8 + j][vkey] = v8p1[j];

        // QK^T from prefetched K fragment
        {
            f32x16 z = {};
            const f32x16 S = __builtin_amdgcn_mfma_f32_32x32x16_bf16(qfrag, kfp, z, 0, 0, 0);
#pragma unroll
            for (int r = 0; r < 16; ++r) {
                const int row = qq * 32 + (r & 3) + 8 * (r >> 2) + 4 * lh;
                Ps[row][sect * 32 + lm] = S[r];
            }
        }
        __syncthreads();   // sync2: Ps ready (Vt also written)

        // issue prefetch for next active tile (latency hides under softmax+PV)
        if (nk < S_LEN) {
            v8p0 = *(const b16x8*)(vbase + (size_t)nk * D_DIM);
            v8p1 = *(const b16x8*)(vbase + (size_t)nk * D_DIM + 8);
            kfp  = *(const b16x8*)(kbase + (size_t)nk * 256);
        }

        // softmax
        {
            const int rg = q0 + srow;
            float s[16];
#pragma unroll
            for (int i = 0; i < 4; ++i) {
                const fx4 t = *(const fx4*)&Ps[srow][skq + i * 4];
#pragma unroll
                for (int j = 0; j < 4; ++j) {
                    const int jg = k0 + skq + i * 4 + j;
                    const bool act = (jg <= rg) || ((rg >= fi) && (jg >= li));
                    s[i * 4 + j] = act ? (t[j] * 0.25f + sp * (float)(jg - rg)) : -3e38f;
                }
            }
            float mloc = -3e38f;
#pragma unroll
            for (int i = 0; i < 16; ++i) mloc = fmaxf(mloc, s[i]);
            mloc = fmaxf(mloc, __shfl_xor(mloc, 1));
            mloc = fmaxf(mloc, __shfl_xor(mloc, 2));
            const float m_old = Mrow[srow];
            const float m_new = fmaxf(m_old, mloc);
            const float alpha = (m_old <= -1e29f) ? 0.f : expf(m_old - m_new);
            float lsum = 0.f;
            b16x8 p0, p1;
#pragma unroll
            for (int i = 0; i < 16; ++i) {
                const float p = (s[i] <= -1e29f) ? 0.f : expf(s[i] - m_new);
                lsum += p;
                if (i < 8) p0[i] = (bf16)p; else p1[i - 8] = (bf16)p;
            }
            lsum += __shfl_xor(lsum, 1);
            lsum += __shfl_xor(lsum, 2);
            *(b16x8*)&Pb[srow][skq]     = p0;
            *(b16x8*)&Pb[srow][skq + 8] = p1;
            if ((lane & 3) == 0) {
                Mrow[srow] = m_new;
                Lrow[srow] = alpha * Lrow[srow] + lsum;
                Arow[srow] = alpha;
            }
        }
        __syncthreads();   // sync3: Pb/Arow ready

        // PV
        {
#pragma unroll
            for (int r = 0; r < 16; ++r) {
                const float al = Arow[qq * 32 + (r & 3) + 8 * (r >> 2) + 4 * lh];
                accO[0][r] *= al;
                accO[1][r] *= al;
            }
            b16x8 Af[4];
#pragma unroll
            for (int ks = 0; ks < 4; ++ks)
                Af[ks] = *(const b16x8*)&Pb[qq * 32 + lm][ks * 16 + lh * 8];
            __builtin_amdgcn_s_setprio(1);
#pragma unroll
            for (int nb = 0; nb < 2; ++nb)
#pragma unroll
                for (int ks = 0; ks < 4; ++ks) {
                    const b16x8 Bf = *(const b16x8*)&Vt[sect * 64 + nb * 32 + lm][ks * 16 + lh * 8];
                    accO[nb] = __builtin_amdgcn_mfma_f32_32x32x16_bf16(Af[ks], Bf, accO[nb], 0, 0, 0);
                }
            __builtin_amdgcn_s_setprio(0);
        }

        k0 = nk;
    }

#pragma unroll
    for (int r = 0; r < 16; ++r) {
        const int row = qq * 32 + (r & 3) + 8 * (r >> 2) + 4 * lh;
        const float L = Lrow[row];
        const float inv = (L > 0.f) ? 1.f / L : 0.f;
        const size_t base = ((size_t)(b * S_LEN + q0 + row)) * EXP_DIM
                          + EXP_DIM / 2 + h * DH_V + sect * 64 + lm;
#pragma unroll
        for (int nb = 0; nb < 2; ++nb)
            concatb[base + nb * 32] = (bf16)(accO[nb][r] * inv);
    }
}

// ---------- workspace layout ----------
static constexpr size_t WS0_OFF = 0;                         // concat: 67,108,864
static constexpr size_t QK_OFF  = 67108864;                  // qkb:     8,388,608
static constexpr size_t VH_OFF  = QK_OFF + 8388608;          // vh:     33,554,432
static constexpr size_t EW_OFF  = VH_OFF + 33554432;         // ew bf16: 8,912,896
static constexpr size_t PW_OFF  = EW_OFF + 8912896;          // pw bf16: 4,194,304
static constexpr size_t WS_NEED = PW_OFF + 4194304;          // 122,159,104

extern "C" void kernel_launch(void* const* d_in, const int* in_sizes, int n_in,
                              void* d_out, int out_size, void* d_ws, size_t ws_size,
                              hipStream_t stream) {
    const float* x         = (const float*)d_in[0];
    const float* norm_w    = (const float*)d_in[1];
    const float* expand_w  = (const float*)d_in[2];
    const float* project_w = (const float*)d_in[3];
    const float* pbm       = (const float*)d_in[4];
    const int*   fip       = (const int*)d_in[5];
    const int*   lip       = (const int*)d_in[6];
    float* out = (float*)d_out;

    if (ws_size < WS_NEED) return;

    char* ws = (char*)d_ws;
    bf16* ws0 = (bf16*)(ws + WS0_OFF);
    bf16* qkb = (bf16*)(ws + QK_OFF);
    bf16* vh  = (bf16*)(ws + VH_OFF);
    bf16* ewb = (bf16*)(ws + EW_OFF);
    bf16* pwb = (bf16*)(ws + PW_OFF);
    bf16* xn  = (bf16*)d_out;            // first 32 MB of d_out as xn scratch

    convert_expand_kernel<<<4352, 256, 0, stream>>>(expand_w, ewb);
    convert_kernel<<<2048, 256, 0, stream>>>(project_w, pwb, 2097152 / 4);
    ln_kernel<<<M_ROWS, 256, 0, stream>>>(x, norm_w, xn);

    // q,k: expand rows 0..255 (legacy 128-tile kernel, identity tile map)
    gemm_bt<0><<<dim3(2, M_ROWS / 128), 256, 0, stream>>>(
        xn, ewb, nullptr, qkb, nullptr, nullptr, M_ROWS, 256, D_DIM);
    // fused lin+pre+geglu: interleaved expand rows 256..4351, 8-phase 256-tile
    gemm256<2><<<dim3(16, M_ROWS / 256), 512, 0, stream>>>(
        xn, ewb + (size_t)256 * D_DIM, nullptr, ws0, vh, nullptr, M_ROWS, 4096, D_DIM);
    attn_kernel<<<dim3(64, 16), 512, 0, stream>>>(qkb, vh, pbm, fip, lip, ws0);
    // out(f32) = concat @ project_w^T + x, 8-phase 256-tile
    gemm256<1><<<dim3(4, M_ROWS / 256), 512, 0, stream>>>(
        ws0, pwb, x, nullptr, nullptr, out, M_ROWS, D_DIM, EXP_DIM);
}

// Round 13
// 505.356 us; speedup vs baseline: 1.0433x; 1.0433x over previous
//
#include <hip/hip_runtime.h>
#include <hip/hip_bf16.h>
#include <cstdint>
#include <cstddef>

// Problem constants (B=16, S=1024, D=1024); inputs f32, output f32 (verified r4)
#define S_LEN   1024
#define D_DIM   1024
#define QK_DIM  128
#define EXP_DIM 2048
#define H_HEADS 8
#define DH_Q    16
#define DH_V    128
#define M_ROWS  16384         // B*S

typedef __bf16 bf16;
typedef __bf16 b16x4 __attribute__((ext_vector_type(4)));
typedef __bf16 b16x8 __attribute__((ext_vector_type(8)));
typedef float  fx4   __attribute__((ext_vector_type(4)));
typedef float  f32x16 __attribute__((ext_vector_type(16)));

// ---------- async global->LDS (16B per lane) ----------
__device__ __forceinline__ void load_lds16(const bf16* g, bf16* l) {
    __builtin_amdgcn_global_load_lds(
        (const __attribute__((address_space(1))) void*)g,
        (__attribute__((address_space(3))) void*)l, 16, 0, 0);
}

// ---------- convert f32 -> bf16, 4 elements/thread ----------
__global__ __launch_bounds__(256) void convert_kernel(const float* __restrict__ src,
                                                      bf16* __restrict__ dst, int n4) {
    const int i = blockIdx.x * 256 + threadIdx.x;
    if (i >= n4) return;
    const fx4 v = ((const fx4*)src)[i];
    b16x4 o;
#pragma unroll
    for (int k = 0; k < 4; ++k) o[k] = (bf16)v[k];
    ((b16x4*)dst)[i] = o;
}

// ---------- convert expand_w f32 -> bf16 with lin/pre row interleave ----------
// rows 0..255 unchanged (q,k). Rows 256..: chunk c: out[256+32c+j] =
// lin[256+16c+j] (j<16) else pre[2304+16c+j-16]. Pairs lin/pre cols into the
// same thread of the fused GEMM (acc[mi][2p] vs acc[mi][2p+1]).
__global__ __launch_bounds__(256) void convert_expand_kernel(const float* __restrict__ src,
                                                             bf16* __restrict__ dst) {
    const int i = blockIdx.x * 256 + threadIdx.x;   // fx4 index; grid covers 4352*256 exactly
    const int orow = i >> 8, col = i & 255;
    int irow;
    if (orow < 256) {
        irow = orow;
    } else {
        const int t = orow - 256;
        const int c = t >> 5, j = t & 31;
        irow = (j < 16) ? (256 + c * 16 + j) : (2304 + c * 16 + (j - 16));
    }
    const fx4 v = ((const fx4*)src)[irow * 256 + col];
    b16x4 o;
#pragma unroll
    for (int k = 0; k < 4; ++k) o[k] = (bf16)v[k];
    ((b16x4*)dst)[i] = o;
}

// ---------- LayerNorm: x (f32) -> xn (bf16) ----------
__global__ __launch_bounds__(256) void ln_kernel(const float* __restrict__ x,
                                                 const float* __restrict__ w,
                                                 bf16* __restrict__ xn) {
    const int row = blockIdx.x;
    const int tid = threadIdx.x;
    const fx4 t = ((const fx4*)x)[(size_t)row * 256 + tid];
    float v[4];
    float s = 0.f, ss = 0.f;
#pragma unroll
    for (int i = 0; i < 4; ++i) { v[i] = t[i]; s += v[i]; ss += v[i] * v[i]; }
#pragma unroll
    for (int off = 32; off >= 1; off >>= 1) {
        s  += __shfl_xor(s,  off);
        ss += __shfl_xor(ss, off);
    }
    __shared__ float ls[4], lss[4];
    const int wave = tid >> 6;
    if ((tid & 63) == 0) { ls[wave] = s; lss[wave] = ss; }
    __syncthreads();
    s  = ls[0]  + ls[1]  + ls[2]  + ls[3];
    ss = lss[0] + lss[1] + lss[2] + lss[3];
    const float mu  = s * (1.f / D_DIM);
    const float var = ss * (1.f / D_DIM) - mu * mu;
    const float r   = rsqrtf(var + 1e-5f);
    const fx4 w4 = ((const fx4*)w)[tid];
    b16x4 o4;
#pragma unroll
    for (int i = 0; i < 4; ++i) o4[i] = (bf16)((v[i] - mu) * r * w4[i]);
    ((b16x4*)(xn + (size_t)row * D_DIM))[tid] = o4;
}

__device__ __forceinline__ float gelu_exact(float x) {
    return 0.5f * x * (1.f + erff(x * 0.70710678118654752f));
}

// ---------- clustered XCD tile map (works for MT%32==0, NT%4==0) ----------
__device__ __forceinline__ void tile_map(int& tm, int& tn) {
    const int NT = gridDim.x, MT = gridDim.y;
    const int lin = blockIdx.y * NT + blockIdx.x;
    if ((MT & 31) == 0 && (NT & 3) == 0) {
        const int xcd = lin & 7, slot = lin >> 3;
        const int MB  = MT >> 3;
        const int cnc = NT >> 2;                 // clusters per row
        const int c = slot >> 4, w = slot & 15;  // 16 blocks per 4x4 cluster
        const int cm = c / cnc, cn = c - cm * cnc;
        tm = xcd * MB + cm * 4 + (w >> 2);
        tn = cn * 4 + (w & 3);
    } else { tm = blockIdx.y; tn = blockIdx.x; }
}

// tile_map for 256-tiles: MT=64 (MT&31==0 holds), NT in {16,4} -> same code.
__device__ __forceinline__ void tile_map256(int& tm, int& tn) {
    const int NT = gridDim.x, MT = gridDim.y;
    const int lin = blockIdx.y * NT + blockIdx.x;
    if ((MT & 31) == 0 && (NT & 3) == 0) {
        const int xcd = lin & 7, slot = lin >> 3;
        const int MB  = MT >> 3;
        const int cnc = NT >> 2;
        const int c = slot >> 4, w = slot & 15;
        const int cm = c / cnc, cn = c - cm * cnc;
        tm = xcd * MB + cm * 4 + (w >> 2);
        tn = cn * 4 + (w & 3);
    } else { tm = blockIdx.y; tn = blockIdx.x; }
}

// ---------- legacy GEMM (m97-style, 128x128, BK=32) -- used for q/k (N=256) ----------
template <int EPI>
__global__ __launch_bounds__(256) void gemm_bt(const bf16* __restrict__ A,
                                               const bf16* __restrict__ W,
                                               const float* __restrict__ R,
                                               bf16* __restrict__ C,
                                               bf16* __restrict__ VH,
                                               float* __restrict__ OutF,
                                               int M, int N, int K) {
    __shared__ bf16 As[128 * 32];
    __shared__ bf16 Ws[128 * 32];
    const int tid  = threadIdx.x;
    const int wave = tid >> 6, lane = tid & 63;
    int tmi, tni;
    tile_map(tmi, tni);
    const int tile_n = tni * 128;
    const int tile_m = tmi * 128;
    const int m_off = (wave >> 1) * 64, n_off = (wave & 1) * 64;

    fx4 acc[4][4] = {};

    const int c0 = wave * 128 + lane;
    const int c1 = c0 + 64;
    const int r0 = c0 >> 2, cc0 = (c0 & 3) * 8;
    const int r1 = c1 >> 2, cc1 = (c1 & 3) * 8;

    const int mrow = lane & 15, quad = lane >> 4;

    for (int k0 = 0; k0 < K; k0 += 32) {
        load_lds16(A + (size_t)(tile_m + r0) * K + k0 + cc0, &As[c0 * 8]);
        load_lds16(A + (size_t)(tile_m + r1) * K + k0 + cc1, &As[c1 * 8]);
        load_lds16(W + (size_t)(tile_n + r0) * K + k0 + cc0, &Ws[c0 * 8]);
        load_lds16(W + (size_t)(tile_n + r1) * K + k0 + cc1, &Ws[c1 * 8]);
        __syncthreads();

        b16x8 af[4], bfr[4];
#pragma unroll
        for (int i = 0; i < 4; ++i) {
            af[i]  = *(const b16x8*)&As[(m_off + i * 16 + mrow) * 32 + quad * 8];
            bfr[i] = *(const b16x8*)&Ws[(n_off + i * 16 + mrow) * 32 + quad * 8];
        }
#pragma unroll
        for (int mi = 0; mi < 4; ++mi)
#pragma unroll
            for (int ni = 0; ni < 4; ++ni)
                acc[mi][ni] = __builtin_amdgcn_mfma_f32_16x16x32_bf16(
                    af[mi], bfr[ni], acc[mi][ni], 0, 0, 0);
        __syncthreads();
    }

    const int lcol = lane & 15, lrow4 = (lane >> 4) * 4;
#pragma unroll
    for (int mi = 0; mi < 4; ++mi)
#pragma unroll
        for (int ni = 0; ni < 4; ++ni)
#pragma unroll
            for (int r = 0; r < 4; ++r) {
                const int gr = tile_m + m_off + mi * 16 + lrow4 + r;
                const int gc = tile_n + n_off + ni * 16 + lcol;
                const float a = acc[mi][ni][r];
                if (EPI == 0) {
                    C[(size_t)gr * N + gc] = (bf16)a;
                } else if (EPI == 1) {
                    const size_t idx = (size_t)gr * N + gc;
                    OutF[idx] = a + R[idx];
                }
            }
}

// ---------- 8-phase 256x256 GEMM, BK=64, 8 waves, counted vmcnt (T3+T4) ----------
// Verified r10: 159 us, MfmaUtil 38%, SQ_LDS_BANK_CONFLICT=0. Frozen.
__device__ __forceinline__ b16x8 lds_frag_swz(const bf16* buf, int r, int colb) {
    const int p = (r << 7) + ((((colb >> 4) ^ r) & 7) << 4) + (colb & 15);
    return *(const b16x8*)((const char*)buf + p);
}

template <int EPI>
__global__ __launch_bounds__(512, 2) void gemm256(const bf16* __restrict__ A,
                                                  const bf16* __restrict__ W,
                                                  const float* __restrict__ R,
                                                  bf16* __restrict__ C,
                                                  bf16* __restrict__ VH,
                                                  float* __restrict__ OutF,
                                                  int M, int N, int K) {
    __shared__ bf16 Abuf[2][16384];   // 2 x 32KB (256 rows x 64 cols)
    __shared__ bf16 Bbuf[2][16384];
    const int tid  = threadIdx.x;
    const int wave = tid >> 6, lane = tid & 63;
    const int wm = wave >> 2, wn = wave & 3;     // 2x4 wave grid
    const int l15 = lane & 15, quad = lane >> 4;

    int tmi, tni;
    tile_map256(tmi, tni);
    const int tile_m = tmi * 256, tile_n = tni * 256;

    const int srow = tid >> 3;                                  // 0..63
    const int scol = (((tid & 7) ^ ((tid >> 3) & 7))) * 8;      // 0..56
    size_t offA[4], offB[4];
#pragma unroll
    for (int s = 0; s < 4; ++s) {
        offA[s] = (size_t)(tile_m + s * 64 + srow) * K + scol;
        offB[s] = (size_t)(tile_n + s * 64 + srow) * K + scol;
    }
    const int ldst = tid * 16;   // linear dest byte offset within each 8KB slot

    fx4 acc[8][4] = {};

    const int ntk = K >> 6;
    // prologue: stage tile 0 into buffer 0, issue order = consumption order:
    // A0, A2 (ph0 A-reads) | B0..B3 (ph0/1/3 B-reads) | A1, A3 (ph2 A-reads)
    {
        char* a0 = (char*)&Abuf[0][0] + ldst;
        char* b0 = (char*)&Bbuf[0][0] + ldst;
        load_lds16(A + offA[0], (bf16*)(a0));
        load_lds16(A + offA[2], (bf16*)(a0 + 16384));
        load_lds16(W + offB[0], (bf16*)(b0));
        load_lds16(W + offB[1], (bf16*)(b0 + 8192));
        load_lds16(W + offB[2], (bf16*)(b0 + 16384));
        load_lds16(W + offB[3], (bf16*)(b0 + 24576));
        load_lds16(A + offA[1], (bf16*)(a0 + 8192));
        load_lds16(A + offA[3], (bf16*)(a0 + 24576));
    }

    for (int t = 0; t < ntk; ++t) {
        const int nb = t & 1;
        const int kt1 = (t + 1) << 6;
        const bool pf = (t + 1 < ntk);
        const bf16* ab = &Abuf[nb][0];
        const bf16* bb = &Bbuf[nb][0];
        char* adst = (char*)&Abuf[nb ^ 1][0] + ldst;
        char* bdst = (char*)&Bbuf[nb ^ 1][0] + ldst;

        b16x8 af[4][2];    // A fragments, one mi-half at a time
        b16x8 bfv[2][2];   // B fragments, one ni-half at a time

        // ---- PH0: wait {A0,A2,B*}(t) | read A mi0-3 + B ni0-1 | stage A0,A2(t+1) | MFMA Q00
        asm volatile("s_waitcnt vmcnt(2)" ::: "memory");
        __builtin_amdgcn_s_barrier();
        __builtin_amdgcn_sched_barrier(0);
#pragma unroll
        for (int mi = 0; mi < 4; ++mi)
#pragma unroll
            for (int kk = 0; kk < 2; ++kk)
                af[mi][kk] = lds_frag_swz(ab, wm * 128 + mi * 16 + l15, kk * 64 + quad * 16);
#pragma unroll
        for (int ni = 0; ni < 2; ++ni)
#pragma unroll
            for (int kk = 0; kk < 2; ++kk)
                bfv[ni][kk] = lds_frag_swz(bb, wn * 64 + ni * 16 + l15, kk * 64 + quad * 16);
        if (pf) {
            load_lds16(A + offA[0] + kt1, (bf16*)(adst));
            load_lds16(A + offA[2] + kt1, (bf16*)(adst + 16384));
        }
        __builtin_amdgcn_s_setprio(1);
#pragma unroll
        for (int mi = 0; mi < 4; ++mi)
#pragma unroll
            for (int ni = 0; ni < 2; ++ni)
#pragma unroll
                for (int kk = 0; kk < 2; ++kk)
                    acc[mi][ni] = __builtin_amdgcn_mfma_f32_16x16x32_bf16(
                        af[mi][kk], bfv[ni][kk], acc[mi][ni], 0, 0, 0);
        __builtin_amdgcn_s_setprio(0);

        // ---- PH1: read B ni2-3 | stage B0..B3(t+1) | MFMA Q01
        __builtin_amdgcn_s_barrier();
        __builtin_amdgcn_sched_barrier(0);
#pragma unroll
        for (int ni = 0; ni < 2; ++ni)
#pragma unroll
            for (int kk = 0; kk < 2; ++kk)
                bfv[ni][kk] = lds_frag_swz(bb, wn * 64 + (ni + 2) * 16 + l15, kk * 64 + quad * 16);
        if (pf) {
            load_lds16(W + offB[0] + kt1, (bf16*)(bdst));
            load_lds16(W + offB[1] + kt1, (bf16*)(bdst + 8192));
            load_lds16(W + offB[2] + kt1, (bf16*)(bdst + 16384));
            load_lds16(W + offB[3] + kt1, (bf16*)(bdst + 24576));
        }
        __builtin_amdgcn_s_setprio(1);
#pragma unroll
        for (int mi = 0; mi < 4; ++mi)
#pragma unroll
            for (int ni = 0; ni < 2; ++ni)
#pragma unroll
                for (int kk = 0; kk < 2; ++kk)
                    acc[mi][ni + 2] = __builtin_amdgcn_mfma_f32_16x16x32_bf16(
                        af[mi][kk], bfv[ni][kk], acc[mi][ni + 2], 0, 0, 0);
        __builtin_amdgcn_s_setprio(0);

        // ---- PH2: wait {A1,A3}(t) | read A mi4-7 | stage A1,A3(t+1) | MFMA (mi4-7 x ni2-3)
        if (pf) asm volatile("s_waitcnt vmcnt(6)" ::: "memory");
        else    asm volatile("s_waitcnt vmcnt(0)" ::: "memory");
        __builtin_amdgcn_s_barrier();
        __builtin_amdgcn_sched_barrier(0);
#pragma unroll
        for (int mi = 0; mi < 4; ++mi)
#pragma unroll
            for (int kk = 0; kk < 2; ++kk)
                af[mi][kk] = lds_frag_swz(ab, wm * 128 + (mi + 4) * 16 + l15, kk * 64 + quad * 16);
        if (pf) {
            load_lds16(A + offA[1] + kt1, (bf16*)(adst + 8192));
            load_lds16(A + offA[3] + kt1, (bf16*)(adst + 24576));
        }
        __builtin_amdgcn_s_setprio(1);
#pragma unroll
        for (int mi = 0; mi < 4; ++mi)
#pragma unroll
            for (int ni = 0; ni < 2; ++ni)
#pragma unroll
                for (int kk = 0; kk < 2; ++kk)
                    acc[mi + 4][ni + 2] = __builtin_amdgcn_mfma_f32_16x16x32_bf16(
                        af[mi][kk], bfv[ni][kk], acc[mi + 4][ni + 2], 0, 0, 0);
        __builtin_amdgcn_s_setprio(0);

        // ---- PH3: read B ni0-1 | MFMA (mi4-7 x ni0-1)
        __builtin_amdgcn_s_barrier();
        __builtin_amdgcn_sched_barrier(0);
#pragma unroll
        for (int ni = 0; ni < 2; ++ni)
#pragma unroll
            for (int kk = 0; kk < 2; ++kk)
                bfv[ni][kk] = lds_frag_swz(bb, wn * 64 + ni * 16 + l15, kk * 64 + quad * 16);
        __builtin_amdgcn_s_setprio(1);
#pragma unroll
        for (int mi = 0; mi < 4; ++mi)
#pragma unroll
            for (int ni = 0; ni < 2; ++ni)
#pragma unroll
                for (int kk = 0; kk < 2; ++kk)
                    acc[mi + 4][ni] = __builtin_amdgcn_mfma_f32_16x16x32_bf16(
                        af[mi][kk], bfv[ni][kk], acc[mi + 4][ni], 0, 0, 0);
        __builtin_amdgcn_s_setprio(0);
        __builtin_amdgcn_s_barrier();
        __builtin_amdgcn_sched_barrier(0);
    }

    // ---- epilogue ----
    const int rbase = tile_m + wm * 128 + quad * 4;
    if (EPI == 2) {
        const int gb = ((tile_n + wn * 64) >> 1) + l15;
#pragma unroll
        for (int mi = 0; mi < 8; ++mi)
#pragma unroll
            for (int np = 0; np < 2; ++np) {
                const int gcol = gb + np * 16;
#pragma unroll
                for (int r = 0; r < 4; ++r) {
                    const int gr = rbase + mi * 16 + r;
                    const float l = acc[mi][2 * np][r];
                    const float p = acc[mi][2 * np + 1][r];
                    const float g = l * gelu_exact(p);
                    if (gcol < 1024) C[(size_t)gr * 2048 + gcol] = (bf16)g;
                    else             VH[(size_t)gr * 1024 + (gcol - 1024)] = (bf16)g;
                }
            }
    } else {
#pragma unroll
        for (int mi = 0; mi < 8; ++mi)
#pragma unroll
            for (int ni = 0; ni < 4; ++ni)
#pragma unroll
                for (int r = 0; r < 4; ++r) {
                    const int gr = rbase + mi * 16 + r;
                    const int gc = tile_n + wn * 64 + ni * 16 + l15;
                    const float a = acc[mi][ni][r];
                    if (EPI == 0) {
                        C[(size_t)gr * N + gc] = (bf16)a;
                    } else {
                        const size_t idx = (size_t)gr * N + gc;
                        OutF[idx] = a + R[idx];
                    }
                }
    }
}

// ---------- MFMA flash attention (QBLK=128, 8 waves; r10-verified body) ----------
// Only change vs r10: expf -> __expf (native v_exp_f32 path). 17 libm expf
// per thread per k-tile (~15-25 inst each) was the dominant softmax VALU
// cost; __expf is 2-3 inst. Error (~1e-6 rel) << bf16 P rounding (~4e-3).
// The s<=-1e29 guard stays: all-masked rows have s-m_new=0 -> exp would be 1.
__global__ __launch_bounds__(512) void attn_kernel(const bf16* __restrict__ qk,
                                                   const bf16* __restrict__ vh,
                                                   const float* __restrict__ pbmv,
                                                   const int* __restrict__ fip,
                                                   const int* __restrict__ lip,
                                                   bf16* __restrict__ concatb) {
    const int lin = blockIdx.y * gridDim.x + blockIdx.x;   // gridDim = (64,16)
    const int xcd = lin & 7, slot = lin >> 3;              // slot 0..127
    const int bh = xcd * 16 + (slot >> 3);
    const int qt = slot & 7;
    const int b = bh >> 3, h = bh & 7;
    const int q0 = qt * 128;
    const int tid  = threadIdx.x;
    const int wave = tid >> 6, lane = tid & 63;
    const int lm = lane & 31, lh = lane >> 5;
    const int qq = wave >> 1, sect = wave & 1;

    __shared__ float Ps[128][68];
    __shared__ bf16  Pb[128][72];
    __shared__ bf16  Vt[128][72];
    __shared__ float Mrow[128], Lrow[128], Arow[128];

    const float pm = pbmv[0];
    const float sp = (pm > 20.f) ? pm : log1pf(expf(pm));
    int fi = fip[0], li = lip[0];
    if (fi >= S_LEN) fi = 0;
    if (li >= S_LEN) li = 0;

    const b16x8 qfrag = *(const b16x8*)(qk
        + ((size_t)(b * S_LEN + q0 + qq * 32 + lm)) * 256 + h * DH_Q + lh * 8);

    f32x16 accO[2] = {};
    if (tid < 128) { Mrow[tid] = -3e38f; Lrow[tid] = 0.f; }

    const int vkey = tid & 63;
    const int vd   = (tid >> 6) * 16;
    const int srow = wave * 16 + (lane >> 2);
    const int skq  = (lane & 3) * 16;

    const int qmax = q0 + 127;
    for (int k0 = 0; k0 < S_LEN; k0 += 64) {
        const bool any = (k0 <= qmax) || ((qmax >= fi) && (k0 + 63 >= li));
        if (!any) continue;

        __syncthreads();

#pragma unroll
        for (int i = 0; i < 2; ++i) {
            const int d0 = vd + i * 8;
            const b16x8 v8 = *(const b16x8*)(vh
                + ((size_t)(b * S_LEN + k0 + vkey)) * D_DIM + h * DH_V + d0);
#pragma unroll
            for (int j = 0; j < 8; ++j) Vt[d0 + j][vkey] = v8[j];
        }

        {
            const b16x8 kfrag = *(const b16x8*)(qk
                + ((size_t)(b * S_LEN + k0 + sect * 32 + lm)) * 256
                + QK_DIM + h * DH_Q + lh * 8);
            f32x16 z = {};
            const f32x16 S = __builtin_amdgcn_mfma_f32_32x32x16_bf16(qfrag, kfrag, z, 0, 0, 0);
#pragma unroll
            for (int r = 0; r < 16; ++r) {
                const int row = qq * 32 + (r & 3) + 8 * (r >> 2) + 4 * lh;
                Ps[row][sect * 32 + lm] = S[r];
            }
        }
        __syncthreads();

        {
            const int rg = q0 + srow;
            float s[16];
#pragma unroll
            for (int i = 0; i < 4; ++i) {
                const fx4 t = *(const fx4*)&Ps[srow][skq + i * 4];
#pragma unroll
                for (int j = 0; j < 4; ++j) {
                    const int jg = k0 + skq + i * 4 + j;
                    const bool act = (jg <= rg) || ((rg >= fi) && (jg >= li));
                    s[i * 4 + j] = act ? (t[j] * 0.25f + sp * (float)(jg - rg)) : -3e38f;
                }
            }
            float mloc = -3e38f;
#pragma unroll
            for (int i = 0; i < 16; ++i) mloc = fmaxf(mloc, s[i]);
            mloc = fmaxf(mloc, __shfl_xor(mloc, 1));
            mloc = fmaxf(mloc, __shfl_xor(mloc, 2));
            const float m_old = Mrow[srow];
            const float m_new = fmaxf(m_old, mloc);
            const float alpha = (m_old <= -1e29f) ? 0.f : __expf(m_old - m_new);
            float lsum = 0.f;
            b16x8 p0, p1;
#pragma unroll
            for (int i = 0; i < 16; ++i) {
                const float p = (s[i] <= -1e29f) ? 0.f : __expf(s[i] - m_new);
                lsum += p;
                if (i < 8) p0[i] = (bf16)p; else p1[i - 8] = (bf16)p;
            }
            lsum += __shfl_xor(lsum, 1);
            lsum += __shfl_xor(lsum, 2);
            *(b16x8*)&Pb[srow][skq]     = p0;
            *(b16x8*)&Pb[srow][skq + 8] = p1;
            if ((lane & 3) == 0) {
                Mrow[srow] = m_new;
                Lrow[srow] = alpha * Lrow[srow] + lsum;
                Arow[srow] = alpha;
            }
        }
        __syncthreads();

        {
#pragma unroll
            for (int r = 0; r < 16; ++r) {
                const float al = Arow[qq * 32 + (r & 3) + 8 * (r >> 2) + 4 * lh];
                accO[0][r] *= al;
                accO[1][r] *= al;
            }
            b16x8 Af[4];
#pragma unroll
            for (int ks = 0; ks < 4; ++ks)
                Af[ks] = *(const b16x8*)&Pb[qq * 32 + lm][ks * 16 + lh * 8];
#pragma unroll
            for (int nb = 0; nb < 2; ++nb)
#pragma unroll
                for (int ks = 0; ks < 4; ++ks) {
                    const b16x8 Bf = *(const b16x8*)&Vt[sect * 64 + nb * 32 + lm][ks * 16 + lh * 8];
                    accO[nb] = __builtin_amdgcn_mfma_f32_32x32x16_bf16(Af[ks], Bf, accO[nb], 0, 0, 0);
                }
        }
    }

#pragma unroll
    for (int r = 0; r < 16; ++r) {
        const int row = qq * 32 + (r & 3) + 8 * (r >> 2) + 4 * lh;
        const float L = Lrow[row];
        const float inv = (L > 0.f) ? 1.f / L : 0.f;
        const size_t base = ((size_t)(b * S_LEN + q0 + row)) * EXP_DIM
                          + EXP_DIM / 2 + h * DH_V + sect * 64 + lm;
#pragma unroll
        for (int nb = 0; nb < 2; ++nb)
            concatb[base + nb * 32] = (bf16)(accO[nb][r] * inv);
    }
}

// ---------- workspace layout ----------
static constexpr size_t WS0_OFF = 0;                         // concat: 67,108,864
static constexpr size_t QK_OFF  = 67108864;                  // qkb:     8,388,608
static constexpr size_t VH_OFF  = QK_OFF + 8388608;          // vh:     33,554,432
static constexpr size_t EW_OFF  = VH_OFF + 33554432;         // ew bf16: 8,912,896
static constexpr size_t PW_OFF  = EW_OFF + 8912896;          // pw bf16: 4,194,304
static constexpr size_t WS_NEED = PW_OFF + 4194304;          // 122,159,104

extern "C" void kernel_launch(void* const* d_in, const int* in_sizes, int n_in,
                              void* d_out, int out_size, void* d_ws, size_t ws_size,
                              hipStream_t stream) {
    const float* x         = (const float*)d_in[0];
    const float* norm_w    = (const float*)d_in[1];
    const float* expand_w  = (const float*)d_in[2];
    const float* project_w = (const float*)d_in[3];
    const float* pbm       = (const float*)d_in[4];
    const int*   fip       = (const int*)d_in[5];
    const int*   lip       = (const int*)d_in[6];
    float* out = (float*)d_out;

    if (ws_size < WS_NEED) return;

    char* ws = (char*)d_ws;
    bf16* ws0 = (bf16*)(ws + WS0_OFF);
    bf16* qkb = (bf16*)(ws + QK_OFF);
    bf16* vh  = (bf16*)(ws + VH_OFF);
    bf16* ewb = (bf16*)(ws + EW_OFF);
    bf16* pwb = (bf16*)(ws + PW_OFF);
    bf16* xn  = (bf16*)d_out;            // first 32 MB of d_out as xn scratch

    convert_expand_kernel<<<4352, 256, 0, stream>>>(expand_w, ewb);
    convert_kernel<<<2048, 256, 0, stream>>>(project_w, pwb, 2097152 / 4);
    ln_kernel<<<M_ROWS, 256, 0, stream>>>(x, norm_w, xn);

    // q,k: expand rows 0..255 (legacy 128-tile kernel, identity tile map)
    gemm_bt<0><<<dim3(2, M_ROWS / 128), 256, 0, stream>>>(
        xn, ewb, nullptr, qkb, nullptr, nullptr, M_ROWS, 256, D_DIM);
    // fused lin+pre+geglu: interleaved expand rows 256..4351, 8-phase 256-tile
    gemm256<2><<<dim3(16, M_ROWS / 256), 512, 0, stream>>>(
        xn, ewb + (size_t)256 * D_DIM, nullptr, ws0, vh, nullptr, M_ROWS, 4096, D_DIM);
    attn_kernel<<<dim3(64, 16), 512, 0, stream>>>(qkb, vh, pbm, fip, lip, ws0);
    // out(f32) = concat @ project_w^T + x, 8-phase 256-tile
    gemm256<1><<<dim3(4, M_ROWS / 256), 512, 0, stream>>>(
        ws0, pwb, x, nullptr, nullptr, out, M_ROWS, D_DIM, EXP_DIM);
}

// Round 14
// 496.107 us; speedup vs baseline: 1.0627x; 1.0186x over previous
//
#include <hip/hip_runtime.h>
#include <hip/hip_bf16.h>
#include <cstdint>
#include <cstddef>

// Problem constants (B=16, S=1024, D=1024); inputs f32, output f32 (verified r4)
#define S_LEN   1024
#define D_DIM   1024
#define QK_DIM  128
#define EXP_DIM 2048
#define H_HEADS 8
#define DH_Q    16
#define DH_V    128
#define M_ROWS  16384         // B*S

typedef __bf16 bf16;
typedef __bf16 b16x4 __attribute__((ext_vector_type(4)));
typedef __bf16 b16x8 __attribute__((ext_vector_type(8)));
typedef float  fx4   __attribute__((ext_vector_type(4)));
typedef float  f32x16 __attribute__((ext_vector_type(16)));

// ---------- async global->LDS (16B per lane) ----------
__device__ __forceinline__ void load_lds16(const bf16* g, bf16* l) {
    __builtin_amdgcn_global_load_lds(
        (const __attribute__((address_space(1))) void*)g,
        (__attribute__((address_space(3))) void*)l, 16, 0, 0);
}

// ---------- convert f32 -> bf16, 4 elements/thread ----------
__global__ __launch_bounds__(256) void convert_kernel(const float* __restrict__ src,
                                                      bf16* __restrict__ dst, int n4) {
    const int i = blockIdx.x * 256 + threadIdx.x;
    if (i >= n4) return;
    const fx4 v = ((const fx4*)src)[i];
    b16x4 o;
#pragma unroll
    for (int k = 0; k < 4; ++k) o[k] = (bf16)v[k];
    ((b16x4*)dst)[i] = o;
}

// ---------- convert expand_w f32 -> bf16 with lin/pre row interleave ----------
// rows 0..255 unchanged (q,k). Rows 256..: chunk c: out[256+32c+j] =
// lin[256+16c+j] (j<16) else pre[2304+16c+j-16]. Pairs lin/pre cols into the
// same thread of the fused GEMM (acc[mi][2p] vs acc[mi][2p+1]).
__global__ __launch_bounds__(256) void convert_expand_kernel(const float* __restrict__ src,
                                                             bf16* __restrict__ dst) {
    const int i = blockIdx.x * 256 + threadIdx.x;   // fx4 index; grid covers 4352*256 exactly
    const int orow = i >> 8, col = i & 255;
    int irow;
    if (orow < 256) {
        irow = orow;
    } else {
        const int t = orow - 256;
        const int c = t >> 5, j = t & 31;
        irow = (j < 16) ? (256 + c * 16 + j) : (2304 + c * 16 + (j - 16));
    }
    const fx4 v = ((const fx4*)src)[irow * 256 + col];
    b16x4 o;
#pragma unroll
    for (int k = 0; k < 4; ++k) o[k] = (bf16)v[k];
    ((b16x4*)dst)[i] = o;
}

// ---------- LayerNorm: x (f32) -> xn (bf16) ----------
__global__ __launch_bounds__(256) void ln_kernel(const float* __restrict__ x,
                                                 const float* __restrict__ w,
                                                 bf16* __restrict__ xn) {
    const int row = blockIdx.x;
    const int tid = threadIdx.x;
    const fx4 t = ((const fx4*)x)[(size_t)row * 256 + tid];
    float v[4];
    float s = 0.f, ss = 0.f;
#pragma unroll
    for (int i = 0; i < 4; ++i) { v[i] = t[i]; s += v[i]; ss += v[i] * v[i]; }
#pragma unroll
    for (int off = 32; off >= 1; off >>= 1) {
        s  += __shfl_xor(s,  off);
        ss += __shfl_xor(ss, off);
    }
    __shared__ float ls[4], lss[4];
    const int wave = tid >> 6;
    if ((tid & 63) == 0) { ls[wave] = s; lss[wave] = ss; }
    __syncthreads();
    s  = ls[0]  + ls[1]  + ls[2]  + ls[3];
    ss = lss[0] + lss[1] + lss[2] + lss[3];
    const float mu  = s * (1.f / D_DIM);
    const float var = ss * (1.f / D_DIM) - mu * mu;
    const float r   = rsqrtf(var + 1e-5f);
    const fx4 w4 = ((const fx4*)w)[tid];
    b16x4 o4;
#pragma unroll
    for (int i = 0; i < 4; ++i) o4[i] = (bf16)((v[i] - mu) * r * w4[i]);
    ((b16x4*)(xn + (size_t)row * D_DIM))[tid] = o4;
}

__device__ __forceinline__ float gelu_exact(float x) {
    return 0.5f * x * (1.f + erff(x * 0.70710678118654752f));
}

// ---------- clustered XCD tile map (works for MT%32==0, NT%4==0) ----------
__device__ __forceinline__ void tile_map(int& tm, int& tn) {
    const int NT = gridDim.x, MT = gridDim.y;
    const int lin = blockIdx.y * NT + blockIdx.x;
    if ((MT & 31) == 0 && (NT & 3) == 0) {
        const int xcd = lin & 7, slot = lin >> 3;
        const int MB  = MT >> 3;
        const int cnc = NT >> 2;                 // clusters per row
        const int c = slot >> 4, w = slot & 15;  // 16 blocks per 4x4 cluster
        const int cm = c / cnc, cn = c - cm * cnc;
        tm = xcd * MB + cm * 4 + (w >> 2);
        tn = cn * 4 + (w & 3);
    } else { tm = blockIdx.y; tn = blockIdx.x; }
}

// tile_map for 256-tiles: MT=64 (MT&31==0 holds), NT in {16,4} -> same code.
__device__ __forceinline__ void tile_map256(int& tm, int& tn) {
    const int NT = gridDim.x, MT = gridDim.y;
    const int lin = blockIdx.y * NT + blockIdx.x;
    if ((MT & 31) == 0 && (NT & 3) == 0) {
        const int xcd = lin & 7, slot = lin >> 3;
        const int MB  = MT >> 3;
        const int cnc = NT >> 2;
        const int c = slot >> 4, w = slot & 15;
        const int cm = c / cnc, cn = c - cm * cnc;
        tm = xcd * MB + cm * 4 + (w >> 2);
        tn = cn * 4 + (w & 3);
    } else { tm = blockIdx.y; tn = blockIdx.x; }
}

// ---------- legacy GEMM (m97-style, 128x128, BK=32) -- used for q/k (N=256) ----------
template <int EPI>
__global__ __launch_bounds__(256) void gemm_bt(const bf16* __restrict__ A,
                                               const bf16* __restrict__ W,
                                               const float* __restrict__ R,
                                               bf16* __restrict__ C,
                                               bf16* __restrict__ VH,
                                               float* __restrict__ OutF,
                                               int M, int N, int K) {
    __shared__ bf16 As[128 * 32];
    __shared__ bf16 Ws[128 * 32];
    const int tid  = threadIdx.x;
    const int wave = tid >> 6, lane = tid & 63;
    int tmi, tni;
    tile_map(tmi, tni);
    const int tile_n = tni * 128;
    const int tile_m = tmi * 128;
    const int m_off = (wave >> 1) * 64, n_off = (wave & 1) * 64;

    fx4 acc[4][4] = {};

    const int c0 = wave * 128 + lane;
    const int c1 = c0 + 64;
    const int r0 = c0 >> 2, cc0 = (c0 & 3) * 8;
    const int r1 = c1 >> 2, cc1 = (c1 & 3) * 8;

    const int mrow = lane & 15, quad = lane >> 4;

    for (int k0 = 0; k0 < K; k0 += 32) {
        load_lds16(A + (size_t)(tile_m + r0) * K + k0 + cc0, &As[c0 * 8]);
        load_lds16(A + (size_t)(tile_m + r1) * K + k0 + cc1, &As[c1 * 8]);
        load_lds16(W + (size_t)(tile_n + r0) * K + k0 + cc0, &Ws[c0 * 8]);
        load_lds16(W + (size_t)(tile_n + r1) * K + k0 + cc1, &Ws[c1 * 8]);
        __syncthreads();

        b16x8 af[4], bfr[4];
#pragma unroll
        for (int i = 0; i < 4; ++i) {
            af[i]  = *(const b16x8*)&As[(m_off + i * 16 + mrow) * 32 + quad * 8];
            bfr[i] = *(const b16x8*)&Ws[(n_off + i * 16 + mrow) * 32 + quad * 8];
        }
#pragma unroll
        for (int mi = 0; mi < 4; ++mi)
#pragma unroll
            for (int ni = 0; ni < 4; ++ni)
                acc[mi][ni] = __builtin_amdgcn_mfma_f32_16x16x32_bf16(
                    af[mi], bfr[ni], acc[mi][ni], 0, 0, 0);
        __syncthreads();
    }

    const int lcol = lane & 15, lrow4 = (lane >> 4) * 4;
#pragma unroll
    for (int mi = 0; mi < 4; ++mi)
#pragma unroll
        for (int ni = 0; ni < 4; ++ni)
#pragma unroll
            for (int r = 0; r < 4; ++r) {
                const int gr = tile_m + m_off + mi * 16 + lrow4 + r;
                const int gc = tile_n + n_off + ni * 16 + lcol;
                const float a = acc[mi][ni][r];
                if (EPI == 0) {
                    C[(size_t)gr * N + gc] = (bf16)a;
                } else if (EPI == 1) {
                    const size_t idx = (size_t)gr * N + gc;
                    OutF[idx] = a + R[idx];
                }
            }
}

// ---------- 8-phase 256x256 GEMM, BK=64, 8 waves, counted vmcnt (T3+T4) ----------
// Verified r10: 159 us, MfmaUtil 38%, SQ_LDS_BANK_CONFLICT=0. Frozen.
__device__ __forceinline__ b16x8 lds_frag_swz(const bf16* buf, int r, int colb) {
    const int p = (r << 7) + ((((colb >> 4) ^ r) & 7) << 4) + (colb & 15);
    return *(const b16x8*)((const char*)buf + p);
}

template <int EPI>
__global__ __launch_bounds__(512, 2) void gemm256(const bf16* __restrict__ A,
                                                  const bf16* __restrict__ W,
                                                  const float* __restrict__ R,
                                                  bf16* __restrict__ C,
                                                  bf16* __restrict__ VH,
                                                  float* __restrict__ OutF,
                                                  int M, int N, int K) {
    __shared__ bf16 Abuf[2][16384];   // 2 x 32KB (256 rows x 64 cols)
    __shared__ bf16 Bbuf[2][16384];
    const int tid  = threadIdx.x;
    const int wave = tid >> 6, lane = tid & 63;
    const int wm = wave >> 2, wn = wave & 3;     // 2x4 wave grid
    const int l15 = lane & 15, quad = lane >> 4;

    int tmi, tni;
    tile_map256(tmi, tni);
    const int tile_m = tmi * 256, tile_n = tni * 256;

    const int srow = tid >> 3;                                  // 0..63
    const int scol = (((tid & 7) ^ ((tid >> 3) & 7))) * 8;      // 0..56
    size_t offA[4], offB[4];
#pragma unroll
    for (int s = 0; s < 4; ++s) {
        offA[s] = (size_t)(tile_m + s * 64 + srow) * K + scol;
        offB[s] = (size_t)(tile_n + s * 64 + srow) * K + scol;
    }
    const int ldst = tid * 16;   // linear dest byte offset within each 8KB slot

    fx4 acc[8][4] = {};

    const int ntk = K >> 6;
    // prologue: stage tile 0 into buffer 0, issue order = consumption order:
    // A0, A2 (ph0 A-reads) | B0..B3 (ph0/1/3 B-reads) | A1, A3 (ph2 A-reads)
    {
        char* a0 = (char*)&Abuf[0][0] + ldst;
        char* b0 = (char*)&Bbuf[0][0] + ldst;
        load_lds16(A + offA[0], (bf16*)(a0));
        load_lds16(A + offA[2], (bf16*)(a0 + 16384));
        load_lds16(W + offB[0], (bf16*)(b0));
        load_lds16(W + offB[1], (bf16*)(b0 + 8192));
        load_lds16(W + offB[2], (bf16*)(b0 + 16384));
        load_lds16(W + offB[3], (bf16*)(b0 + 24576));
        load_lds16(A + offA[1], (bf16*)(a0 + 8192));
        load_lds16(A + offA[3], (bf16*)(a0 + 24576));
    }

    for (int t = 0; t < ntk; ++t) {
        const int nb = t & 1;
        const int kt1 = (t + 1) << 6;
        const bool pf = (t + 1 < ntk);
        const bf16* ab = &Abuf[nb][0];
        const bf16* bb = &Bbuf[nb][0];
        char* adst = (char*)&Abuf[nb ^ 1][0] + ldst;
        char* bdst = (char*)&Bbuf[nb ^ 1][0] + ldst;

        b16x8 af[4][2];    // A fragments, one mi-half at a time
        b16x8 bfv[2][2];   // B fragments, one ni-half at a time

        // ---- PH0: wait {A0,A2,B*}(t) | read A mi0-3 + B ni0-1 | stage A0,A2(t+1) | MFMA Q00
        asm volatile("s_waitcnt vmcnt(2)" ::: "memory");
        __builtin_amdgcn_s_barrier();
        __builtin_amdgcn_sched_barrier(0);
#pragma unroll
        for (int mi = 0; mi < 4; ++mi)
#pragma unroll
            for (int kk = 0; kk < 2; ++kk)
                af[mi][kk] = lds_frag_swz(ab, wm * 128 + mi * 16 + l15, kk * 64 + quad * 16);
#pragma unroll
        for (int ni = 0; ni < 2; ++ni)
#pragma unroll
            for (int kk = 0; kk < 2; ++kk)
                bfv[ni][kk] = lds_frag_swz(bb, wn * 64 + ni * 16 + l15, kk * 64 + quad * 16);
        if (pf) {
            load_lds16(A + offA[0] + kt1, (bf16*)(adst));
            load_lds16(A + offA[2] + kt1, (bf16*)(adst + 16384));
        }
        __builtin_amdgcn_s_setprio(1);
#pragma unroll
        for (int mi = 0; mi < 4; ++mi)
#pragma unroll
            for (int ni = 0; ni < 2; ++ni)
#pragma unroll
                for (int kk = 0; kk < 2; ++kk)
                    acc[mi][ni] = __builtin_amdgcn_mfma_f32_16x16x32_bf16(
                        af[mi][kk], bfv[ni][kk], acc[mi][ni], 0, 0, 0);
        __builtin_amdgcn_s_setprio(0);

        // ---- PH1: read B ni2-3 | stage B0..B3(t+1) | MFMA Q01
        __builtin_amdgcn_s_barrier();
        __builtin_amdgcn_sched_barrier(0);
#pragma unroll
        for (int ni = 0; ni < 2; ++ni)
#pragma unroll
            for (int kk = 0; kk < 2; ++kk)
                bfv[ni][kk] = lds_frag_swz(bb, wn * 64 + (ni + 2) * 16 + l15, kk * 64 + quad * 16);
        if (pf) {
            load_lds16(W + offB[0] + kt1, (bf16*)(bdst));
            load_lds16(W + offB[1] + kt1, (bf16*)(bdst + 8192));
            load_lds16(W + offB[2] + kt1, (bf16*)(bdst + 16384));
            load_lds16(W + offB[3] + kt1, (bf16*)(bdst + 24576));
        }
        __builtin_amdgcn_s_setprio(1);
#pragma unroll
        for (int mi = 0; mi < 4; ++mi)
#pragma unroll
            for (int ni = 0; ni < 2; ++ni)
#pragma unroll
                for (int kk = 0; kk < 2; ++kk)
                    acc[mi][ni + 2] = __builtin_amdgcn_mfma_f32_16x16x32_bf16(
                        af[mi][kk], bfv[ni][kk], acc[mi][ni + 2], 0, 0, 0);
        __builtin_amdgcn_s_setprio(0);

        // ---- PH2: wait {A1,A3}(t) | read A mi4-7 | stage A1,A3(t+1) | MFMA (mi4-7 x ni2-3)
        if (pf) asm volatile("s_waitcnt vmcnt(6)" ::: "memory");
        else    asm volatile("s_waitcnt vmcnt(0)" ::: "memory");
        __builtin_amdgcn_s_barrier();
        __builtin_amdgcn_sched_barrier(0);
#pragma unroll
        for (int mi = 0; mi < 4; ++mi)
#pragma unroll
            for (int kk = 0; kk < 2; ++kk)
                af[mi][kk] = lds_frag_swz(ab, wm * 128 + (mi + 4) * 16 + l15, kk * 64 + quad * 16);
        if (pf) {
            load_lds16(A + offA[1] + kt1, (bf16*)(adst + 8192));
            load_lds16(A + offA[3] + kt1, (bf16*)(adst + 24576));
        }
        __builtin_amdgcn_s_setprio(1);
#pragma unroll
        for (int mi = 0; mi < 4; ++mi)
#pragma unroll
            for (int ni = 0; ni < 2; ++ni)
#pragma unroll
                for (int kk = 0; kk < 2; ++kk)
                    acc[mi + 4][ni + 2] = __builtin_amdgcn_mfma_f32_16x16x32_bf16(
                        af[mi][kk], bfv[ni][kk], acc[mi + 4][ni + 2], 0, 0, 0);
        __builtin_amdgcn_s_setprio(0);

        // ---- PH3: read B ni0-1 | MFMA (mi4-7 x ni0-1)
        __builtin_amdgcn_s_barrier();
        __builtin_amdgcn_sched_barrier(0);
#pragma unroll
        for (int ni = 0; ni < 2; ++ni)
#pragma unroll
            for (int kk = 0; kk < 2; ++kk)
                bfv[ni][kk] = lds_frag_swz(bb, wn * 64 + ni * 16 + l15, kk * 64 + quad * 16);
        __builtin_amdgcn_s_setprio(1);
#pragma unroll
        for (int mi = 0; mi < 4; ++mi)
#pragma unroll
            for (int ni = 0; ni < 2; ++ni)
#pragma unroll
                for (int kk = 0; kk < 2; ++kk)
                    acc[mi + 4][ni] = __builtin_amdgcn_mfma_f32_16x16x32_bf16(
                        af[mi][kk], bfv[ni][kk], acc[mi + 4][ni], 0, 0, 0);
        __builtin_amdgcn_s_setprio(0);
        __builtin_amdgcn_s_barrier();
        __builtin_amdgcn_sched_barrier(0);
    }

    // ---- epilogue ----
    const int rbase = tile_m + wm * 128 + quad * 4;
    if (EPI == 2) {
        const int gb = ((tile_n + wn * 64) >> 1) + l15;
#pragma unroll
        for (int mi = 0; mi < 8; ++mi)
#pragma unroll
            for (int np = 0; np < 2; ++np) {
                const int gcol = gb + np * 16;
#pragma unroll
                for (int r = 0; r < 4; ++r) {
                    const int gr = rbase + mi * 16 + r;
                    const float l = acc[mi][2 * np][r];
                    const float p = acc[mi][2 * np + 1][r];
                    const float g = l * gelu_exact(p);
                    if (gcol < 1024) C[(size_t)gr * 2048 + gcol] = (bf16)g;
                    else             VH[(size_t)gr * 1024 + (gcol - 1024)] = (bf16)g;
                }
            }
    } else {
#pragma unroll
        for (int mi = 0; mi < 8; ++mi)
#pragma unroll
            for (int ni = 0; ni < 4; ++ni)
#pragma unroll
                for (int r = 0; r < 4; ++r) {
                    const int gr = rbase + mi * 16 + r;
                    const int gc = tile_n + wn * 64 + ni * 16 + l15;
                    const float a = acc[mi][ni][r];
                    if (EPI == 0) {
                        C[(size_t)gr * N + gc] = (bf16)a;
                    } else {
                        const size_t idx = (size_t)gr * N + gc;
                        OutF[idx] = a + R[idx];
                    }
                }
    }
}

// ---------- MFMA flash attention (QBLK=128, 8 waves, swapped QK^T in-reg softmax) ----------
// QK^T computed as mfma(K, Q): output col = q = lane&31 -> each lane owns ONE
// q-row (q0+qq*32+lm) and 16 keys (k = k0+sect*32+(r&3)+8*(r>>2)+4*lh).
// Softmax fully in-register: mask+bias+max over 16, shfl_xor(32) merges lh
// halves, cross-sect tile max via 1KB Msect exchange (uses the same sync slot
// the old Ps round-trip needed -> still 3 syncs/tile). Running m,l are
// per-lane registers (identical in all 4 lanes of a q-row by construction).
// P packed to bf16 fragments via 8 u32 shfl_xor(32): for lane lh, block
// (2ks+lh) of its sect half = [own/partner u32[4ks..4ks+1] | ...] exactly
// matching the r10-verified PV A-fragment layout Pb[q][ks*16+lh*8]. PV reads
// its own sect's 2 fragments from registers, other sect's 2 from Pb. PV,
// Vt staging, epilogue addressing byte-identical to r10. Final L = sum of 4
// per-lane partials via shfl + Lsect. Ps (35KB) eliminated from LDS.
__global__ __launch_bounds__(512) void attn_kernel(const bf16* __restrict__ qk,
                                                   const bf16* __restrict__ vh,
                                                   const float* __restrict__ pbmv,
                                                   const int* __restrict__ fip,
                                                   const int* __restrict__ lip,
                                                   bf16* __restrict__ concatb) {
    const int lin = blockIdx.y * gridDim.x + blockIdx.x;   // gridDim = (64,16)
    const int xcd = lin & 7, slot = lin >> 3;              // slot 0..127
    const int bh = xcd * 16 + (slot >> 3);
    const int qt = slot & 7;
    const int b = bh >> 3, h = bh & 7;
    const int q0 = qt * 128;
    const int tid  = threadIdx.x;
    const int wave = tid >> 6, lane = tid & 63;
    const int lm = lane & 31, lh = lane >> 5;
    const int qq = wave >> 1, sect = wave & 1;

    __shared__ bf16  Pb[128][72];
    __shared__ bf16  Vt[128][72];
    __shared__ float Msect[2][128];
    __shared__ float Lsect[2][128];
    __shared__ float Arow[128];

    const float pm = pbmv[0];
    const float sp = (pm > 20.f) ? pm : log1pf(expf(pm));
    int fi = fip[0], li = lip[0];
    if (fi >= S_LEN) fi = 0;
    if (li >= S_LEN) li = 0;

    const b16x8 qfrag = *(const b16x8*)(qk
        + ((size_t)(b * S_LEN + q0 + qq * 32 + lm)) * 256 + h * DH_Q + lh * 8);

    f32x16 accO[2] = {};
    float m_run = -3e38f, l_run = 0.f;

    const int vkey = tid & 63;
    const int vd   = (tid >> 6) * 16;
    const int myrow = qq * 32 + lm;   // this lane's q-row (swapped layout)
    const int rg    = q0 + myrow;

    const int qmax = q0 + 127;
    for (int k0 = 0; k0 < S_LEN; k0 += 64) {
        const bool any = (k0 <= qmax) || ((qmax >= fi) && (k0 + 63 >= li));
        if (!any) continue;

        __syncthreads();   // sync a: prev PV done with Vt; prev Msect reads done

#pragma unroll
        for (int i = 0; i < 2; ++i) {
            const int d0 = vd + i * 8;
            const b16x8 v8 = *(const b16x8*)(vh
                + ((size_t)(b * S_LEN + k0 + vkey)) * D_DIM + h * DH_V + d0);
#pragma unroll
            for (int j = 0; j < 8; ++j) Vt[d0 + j][vkey] = v8[j];
        }

        // QK^T swapped: A=K (rows=keys), B=Q (cols=q) -> lane owns q=myrow
        float s[16];
        float mx = -3e38f;
        {
            const b16x8 kfrag = *(const b16x8*)(qk
                + ((size_t)(b * S_LEN + k0 + sect * 32 + lm)) * 256
                + QK_DIM + h * DH_Q + lh * 8);
            f32x16 z = {};
            const f32x16 S = __builtin_amdgcn_mfma_f32_32x32x16_bf16(kfrag, qfrag, z, 0, 0, 0);
#pragma unroll
            for (int r = 0; r < 16; ++r) {
                const int jg = k0 + sect * 32 + (r & 3) + 8 * (r >> 2) + 4 * lh;
                const bool act = (jg <= rg) || ((rg >= fi) && (jg >= li));
                s[r] = act ? (S[r] * 0.25f + sp * (float)(jg - rg)) : -3e38f;
                mx = fmaxf(mx, s[r]);
            }
        }
        mx = fmaxf(mx, __shfl_xor(mx, 32));        // merge lh halves (32-key max)
        if (lh == 0) Msect[sect][myrow] = mx;
        __syncthreads();   // sync b: Msect ready

        // in-register softmax (per-lane state; identical across the row's lanes)
        const float m_tile = fmaxf(Msect[0][myrow], Msect[1][myrow]);
        const float m_new  = fmaxf(m_run, m_tile);
        const float alpha  = (m_run <= -1e29f) ? 0.f : __expf(m_run - m_new);
        l_run *= alpha;
        bf16 pbv[16];
#pragma unroll
        for (int r = 0; r < 16; ++r) {
            const float p = (s[r] <= -1e29f) ? 0.f : __expf(s[r] - m_new);
            l_run += p;
            pbv[r] = (bf16)p;
        }
        m_run = m_new;
        if (sect == 0 && lh == 0) Arow[myrow] = alpha;

        // pack P into PV A-fragments: own u32s + partner (lane^32) u32s
        uint32_t ou[8], pu[8];
#pragma unroll
        for (int i = 0; i < 8; ++i) {
            union { bf16 hx[2]; uint32_t u; } c;
            c.hx[0] = pbv[2 * i]; c.hx[1] = pbv[2 * i + 1];
            ou[i] = c.u;
        }
#pragma unroll
        for (int i = 0; i < 8; ++i) pu[i] = (uint32_t)__shfl_xor((int)ou[i], 32);
        b16x8 pa[2];
#pragma unroll
        for (int ks = 0; ks < 2; ++ks) {
            union { uint32_t u[4]; b16x8 v; } a;
            if (lh == 0) {
                a.u[0] = ou[4 * ks];     a.u[1] = ou[4 * ks + 1];
                a.u[2] = pu[4 * ks];     a.u[3] = pu[4 * ks + 1];
            } else {
                a.u[0] = pu[4 * ks + 2]; a.u[1] = pu[4 * ks + 3];
                a.u[2] = ou[4 * ks + 2]; a.u[3] = ou[4 * ks + 3];
            }
            pa[ks] = a.v;
            *(b16x8*)&Pb[myrow][sect * 32 + ks * 16 + lh * 8] = pa[ks];
        }
        __syncthreads();   // sync c: Pb/Arow ready

        // PV (r10-verified structure; 2 of 4 A-fragments come from registers)
        {
#pragma unroll
            for (int r = 0; r < 16; ++r) {
                const float al = Arow[qq * 32 + (r & 3) + 8 * (r >> 2) + 4 * lh];
                accO[0][r] *= al;
                accO[1][r] *= al;
            }
            b16x8 Af[4];
            if (sect == 0) {
                Af[0] = pa[0];
                Af[1] = pa[1];
                Af[2] = *(const b16x8*)&Pb[qq * 32 + lm][2 * 16 + lh * 8];
                Af[3] = *(const b16x8*)&Pb[qq * 32 + lm][3 * 16 + lh * 8];
            } else {
                Af[0] = *(const b16x8*)&Pb[qq * 32 + lm][0 * 16 + lh * 8];
                Af[1] = *(const b16x8*)&Pb[qq * 32 + lm][1 * 16 + lh * 8];
                Af[2] = pa[0];
                Af[3] = pa[1];
            }
#pragma unroll
            for (int nb = 0; nb < 2; ++nb)
#pragma unroll
                for (int ks = 0; ks < 4; ++ks) {
                    const b16x8 Bf = *(const b16x8*)&Vt[sect * 64 + nb * 32 + lm][ks * 16 + lh * 8];
                    accO[nb] = __builtin_amdgcn_mfma_f32_32x32x16_bf16(Af[ks], Bf, accO[nb], 0, 0, 0);
                }
        }
    }

    // final L: combine lh partials (shfl) then sect partials (LDS)
    {
        const float lt = l_run + __shfl_xor(l_run, 32);
        if (lh == 0) Lsect[sect][myrow] = lt;
    }
    __syncthreads();

#pragma unroll
    for (int r = 0; r < 16; ++r) {
        const int row = qq * 32 + (r & 3) + 8 * (r >> 2) + 4 * lh;
        const float L = Lsect[0][row] + Lsect[1][row];
        const float inv = (L > 0.f) ? 1.f / L : 0.f;
        const size_t base = ((size_t)(b * S_LEN + q0 + row)) * EXP_DIM
                          + EXP_DIM / 2 + h * DH_V + sect * 64 + lm;
#pragma unroll
        for (int nb = 0; nb < 2; ++nb)
            concatb[base + nb * 32] = (bf16)(accO[nb][r] * inv);
    }
}

// ---------- workspace layout ----------
static constexpr size_t WS0_OFF = 0;                         // concat: 67,108,864
static constexpr size_t QK_OFF  = 67108864;                  // qkb:     8,388,608
static constexpr size_t VH_OFF  = QK_OFF + 8388608;          // vh:     33,554,432
static constexpr size_t EW_OFF  = VH_OFF + 33554432;         // ew bf16: 8,912,896
static constexpr size_t PW_OFF  = EW_OFF + 8912896;          // pw bf16: 4,194,304
static constexpr size_t WS_NEED = PW_OFF + 4194304;          // 122,159,104

extern "C" void kernel_launch(void* const* d_in, const int* in_sizes, int n_in,
                              void* d_out, int out_size, void* d_ws, size_t ws_size,
                              hipStream_t stream) {
    const float* x         = (const float*)d_in[0];
    const float* norm_w    = (const float*)d_in[1];
    const float* expand_w  = (const float*)d_in[2];
    const float* project_w = (const float*)d_in[3];
    const float* pbm       = (const float*)d_in[4];
    const int*   fip       = (const int*)d_in[5];
    const int*   lip       = (const int*)d_in[6];
    float* out = (float*)d_out;

    if (ws_size < WS_NEED) return;

    char* ws = (char*)d_ws;
    bf16* ws0 = (bf16*)(ws + WS0_OFF);
    bf16* qkb = (bf16*)(ws + QK_OFF);
    bf16* vh  = (bf16*)(ws + VH_OFF);
    bf16* ewb = (bf16*)(ws + EW_OFF);
    bf16* pwb = (bf16*)(ws + PW_OFF);
    bf16* xn  = (bf16*)d_out;            // first 32 MB of d_out as xn scratch

    convert_expand_kernel<<<4352, 256, 0, stream>>>(expand_w, ewb);
    convert_kernel<<<2048, 256, 0, stream>>>(project_w, pwb, 2097152 / 4);
    ln_kernel<<<M_ROWS, 256, 0, stream>>>(x, norm_w, xn);

    // q,k: expand rows 0..255 (legacy 128-tile kernel, identity tile map)
    gemm_bt<0><<<dim3(2, M_ROWS / 128), 256, 0, stream>>>(
        xn, ewb, nullptr, qkb, nullptr, nullptr, M_ROWS, 256, D_DIM);
    // fused lin+pre+geglu: interleaved expand rows 256..4351, 8-phase 256-tile
    gemm256<2><<<dim3(16, M_ROWS / 256), 512, 0, stream>>>(
        xn, ewb + (size_t)256 * D_DIM, nullptr, ws0, vh, nullptr, M_ROWS, 4096, D_DIM);
    attn_kernel<<<dim3(64, 16), 512, 0, stream>>>(qkb, vh, pbm, fip, lip, ws0);
    // out(f32) = concat @ project_w^T + x, 8-phase 256-tile
    gemm256<1><<<dim3(4, M_ROWS / 256), 512, 0, stream>>>(
        ws0, pwb, x, nullptr, nullptr, out, M_ROWS, D_DIM, EXP_DIM);
}